// Round 13
// baseline (247.915 us; speedup 1.0000x reference)
//
#include <hip/hip_runtime.h>
#include <hip/hip_fp16.h>

// ---------------------------------------------------------------------------
// BasketballGNN round 13:
//   - revert R12's P1+gemm1 merge (regressed; heterogeneous blocks serialize)
//   - P3 histogram pass eliminated (P2a writes offsets to hoff, hist keeps
//     counts; P3 reads its column instead of re-histogramming dst)
//   - aggregation interleaves 4 nodes per wave: 4 independent gathers in
//     flight, edge loop = max(deg) not sum(deg) over the wave's nodes
//   - P4 keeps LDS ebuf staging (single bedge read)
// ---------------------------------------------------------------------------

#define P3CAP 3200   // >= chunk (3128 for E=800k)
#define P4CAP 8192   // >= max edges per 256-node bucket (avg 4082 for E=800k)

typedef float vf4 __attribute__((ext_vector_type(4)));

__device__ __forceinline__ int block_scan_incl(int v, int* s, int t) {
    s[t] = v;
    __syncthreads();
#pragma unroll
    for (int d = 1; d < 256; d <<= 1) {
        int a = (t >= d) ? s[t - d] : 0;
        __syncthreads();
        s[t] += a;
        __syncthreads();
    }
    return s[t];
}

__host__ __device__ __forceinline__ int chunk_of(int E) {
    return (((E + 255) / 256) + 3) & ~3;
}

// P1: per-chunk bucket histogram (counts kept for P3). grid=256.
__global__ __launch_bounds__(256) void part_hist_kernel(
    const int* __restrict__ dst, int* __restrict__ hist, int E, int nbuckets)
{
    __shared__ int lh[256];
    const int t = threadIdx.x;
    lh[t] = 0;
    __syncthreads();
    const int chunk = chunk_of(E);
    const int e0 = blockIdx.x * chunk;
    const int e1 = min(E, e0 + chunk);
    int e = e0 + t * 4;
    for (; e + 3 < e1; e += 1024) {
        const int4 d4 = *(const int4*)&dst[e];
        atomicAdd(&lh[d4.x >> 8], 1);
        atomicAdd(&lh[d4.y >> 8], 1);
        atomicAdd(&lh[d4.z >> 8], 1);
        atomicAdd(&lh[d4.w >> 8], 1);
    }
    for (; e < e1; ++e) atomicAdd(&lh[dst[e] >> 8], 1);
    __syncthreads();
    if (t < nbuckets) hist[t * 256 + blockIdx.x] = lh[t];
}

// P2a: per-bucket scan; offsets -> hoff (hist counts preserved), totals -> btot.
__global__ __launch_bounds__(256) void part_scan_kernel(
    const int* __restrict__ hist, int* __restrict__ hoff, int* __restrict__ btot)
{
    __shared__ int s[256];
    const int t = threadIdx.x;
    const int v = hist[blockIdx.x * 256 + t];
    const int inc = block_scan_incl(v, s, t);
    hoff[blockIdx.x * 256 + t] = inc - v;
    if (t == 255) btot[blockIdx.x] = inc;
}

// P3: single-pass LDS counting-sort of each chunk (counts read from hist).
__global__ __launch_bounds__(256) void part_scatter_kernel(
    const int* __restrict__ src, const int* __restrict__ dst,
    const int* __restrict__ hist, const int* __restrict__ hoff,
    const int* __restrict__ btot, int* __restrict__ bedge, int E, int nbuckets)
{
    __shared__ int gb[256], cur[256], s[256];
    __shared__ int stage[P3CAP];
    const int t = threadIdx.x;

    const int bv = (t < nbuckets) ? btot[t] : 0;
    const int binc = block_scan_incl(bv, s, t);
    const int bbase_t = binc - bv;
    __syncthreads();

    const int cnt_t = (t < nbuckets) ? hist[t * 256 + blockIdx.x] : 0;
    const int inc = block_scan_incl(cnt_t, s, t);
    const int excl = inc - cnt_t;
    cur[t] = excl;
    if (t < nbuckets) gb[t] = bbase_t + hoff[t * 256 + blockIdx.x] - excl;
    __syncthreads();

    const int chunk = chunk_of(E);
    const int e0 = blockIdx.x * chunk;
    const int e1 = min(E, e0 + chunk);
    {
        int e = e0 + t * 4;
        for (; e + 3 < e1; e += 1024) {
            const int4 d4 = *(const int4*)&dst[e];
            const int4 s4 = *(const int4*)&src[e];
            int r, b;
            b = d4.x >> 8; r = atomicAdd(&cur[b], 1);
            stage[r] = (s4.x & 0xffff) | ((d4.x & 255) << 16) | (b << 24);
            b = d4.y >> 8; r = atomicAdd(&cur[b], 1);
            stage[r] = (s4.y & 0xffff) | ((d4.y & 255) << 16) | (b << 24);
            b = d4.z >> 8; r = atomicAdd(&cur[b], 1);
            stage[r] = (s4.z & 0xffff) | ((d4.z & 255) << 16) | (b << 24);
            b = d4.w >> 8; r = atomicAdd(&cur[b], 1);
            stage[r] = (s4.w & 0xffff) | ((d4.w & 255) << 16) | (b << 24);
        }
        for (; e < e1; ++e) {
            const int dv = dst[e];
            const int b = dv >> 8;
            const int r = atomicAdd(&cur[b], 1);
            stage[r] = (src[e] & 0xffff) | ((dv & 255) << 16) | (b << 24);
        }
    }
    __syncthreads();
    const int cnt = e1 - e0;
    for (int i = t; i < cnt; i += 256) {
        const int p = stage[i];
        const int bucket = (int)((unsigned)p >> 24);
        bedge[gb[bucket] + i] = p;
    }
}

// P4: one block per bucket; bedge slice staged in LDS; -> csr, off, dis.
__global__ __launch_bounds__(256) void bucket_csr_kernel(
    const int* __restrict__ bedge, const int* __restrict__ btot,
    int* __restrict__ csr, int* __restrict__ off, float* __restrict__ dis,
    int N, int nbuckets)
{
    __shared__ int deg[256], cur[256], s[256];
    __shared__ int e01[2];
    __shared__ int ebuf[P4CAP];
    __shared__ int lcsr[P4CAP];
    const int t = threadIdx.x;
    const int b = blockIdx.x;

    const int bv = (t < nbuckets) ? btot[t] : 0;
    const int binc = block_scan_incl(bv, s, t);
    if (t == b) { e01[0] = binc - bv; e01[1] = binc; }
    deg[t] = 0;
    __syncthreads();
    const int e0 = e01[0], e1 = e01[1];
    const int m = e1 - e0;

    for (int i = t; i < m; i += 256) ebuf[i] = bedge[e0 + i];
    __syncthreads();
    for (int i = t; i < m; i += 256)
        atomicAdd(&deg[(ebuf[i] >> 16) & 255], 1);
    __syncthreads();
    const int v = deg[t];
    const int inc = block_scan_incl(v, s, t);
    cur[t] = inc - v;
    const int node = (b << 8) + t;
    if (node < N) {
        off[node + 1] = e0 + inc;
        dis[node] = rsqrtf((float)v + 1.0f);
        if (node == 0) off[0] = 0;
    }
    __syncthreads();
    for (int i = t; i < m; i += 256) {
        const int p = ebuf[i];
        const int pos = atomicAdd(&cur[(p >> 16) & 255], 1);
        lcsr[pos] = p & 0xffff;
    }
    __syncthreads();
    for (int i = t; i < m; i += 256)
        csr[e0 + i] = lcsr[i];
}

// GEMM (layer 1): hp[i,:] = fp16((in[i,:] @ W) * dis[i]).  TR=2 tile.
template<int K, int C, int TR>
__global__ __launch_bounds__(256) void gemm_scale_kernel(
    const float* __restrict__ in, const float* __restrict__ W,
    const float* __restrict__ dis, __half* __restrict__ hp, int N)
{
    constexpr int TX = C / 4;
    constexpr int R  = (256 / TX) * TR;
    __shared__ float Wl[K * C];

    const int t = threadIdx.x;
    for (int i = t; i < K * C / 4; i += 256)
        ((float4*)Wl)[i] = ((const float4*)W)[i];
    __syncthreads();

    const int tx = t % TX, ty = t / TX;
    const int cb = tx * 4;
    const int row0 = blockIdx.x * R + ty * TR;

    float acc[TR][4];
#pragma unroll
    for (int r = 0; r < TR; ++r) acc[r][0] = acc[r][1] = acc[r][2] = acc[r][3] = 0.0f;

    auto store_row = [&](int row, int r) {
        const float d = dis[row];
        __half2 h0 = __float22half2_rn(make_float2(acc[r][0] * d, acc[r][1] * d));
        __half2 h1 = __float22half2_rn(make_float2(acc[r][2] * d, acc[r][3] * d));
        uint2 u;
        u.x = *(unsigned*)&h0;
        u.y = *(unsigned*)&h1;
        *(uint2*)&hp[(size_t)row * C + cb] = u;
    };

    if (row0 + TR <= N) {
        const float* inp = in + (size_t)row0 * K;
#pragma unroll 4
        for (int k4 = 0; k4 < K / 4; ++k4) {
            float4 w0 = *(const float4*)&Wl[(k4 * 4 + 0) * C + cb];
            float4 w1 = *(const float4*)&Wl[(k4 * 4 + 1) * C + cb];
            float4 w2 = *(const float4*)&Wl[(k4 * 4 + 2) * C + cb];
            float4 w3 = *(const float4*)&Wl[(k4 * 4 + 3) * C + cb];
#pragma unroll
            for (int r = 0; r < TR; ++r) {
                const vf4 a = __builtin_nontemporal_load((const vf4*)&inp[r * K + k4 * 4]);
                acc[r][0] = fmaf(a.x, w0.x, acc[r][0]);
                acc[r][1] = fmaf(a.x, w0.y, acc[r][1]);
                acc[r][2] = fmaf(a.x, w0.z, acc[r][2]);
                acc[r][3] = fmaf(a.x, w0.w, acc[r][3]);
                acc[r][0] = fmaf(a.y, w1.x, acc[r][0]);
                acc[r][1] = fmaf(a.y, w1.y, acc[r][1]);
                acc[r][2] = fmaf(a.y, w1.z, acc[r][2]);
                acc[r][3] = fmaf(a.y, w1.w, acc[r][3]);
                acc[r][0] = fmaf(a.z, w2.x, acc[r][0]);
                acc[r][1] = fmaf(a.z, w2.y, acc[r][1]);
                acc[r][2] = fmaf(a.z, w2.z, acc[r][2]);
                acc[r][3] = fmaf(a.z, w2.w, acc[r][3]);
                acc[r][0] = fmaf(a.w, w3.x, acc[r][0]);
                acc[r][1] = fmaf(a.w, w3.y, acc[r][1]);
                acc[r][2] = fmaf(a.w, w3.z, acc[r][2]);
                acc[r][3] = fmaf(a.w, w3.w, acc[r][3]);
            }
        }
#pragma unroll
        for (int r = 0; r < TR; ++r) store_row(row0 + r, r);
    } else {
        for (int k = 0; k < K; ++k) {
            const float4 w4 = *(const float4*)&Wl[k * C + cb];
#pragma unroll
            for (int r = 0; r < TR; ++r) {
                const int row = row0 + r;
                const float a = (row < N) ? in[(size_t)row * K + k] : 0.0f;
                acc[r][0] = fmaf(a, w4.x, acc[r][0]);
                acc[r][1] = fmaf(a, w4.y, acc[r][1]);
                acc[r][2] = fmaf(a, w4.z, acc[r][2]);
                acc[r][3] = fmaf(a, w4.w, acc[r][3]);
            }
        }
#pragma unroll
        for (int r = 0; r < TR; ++r)
            if (row0 + r < N) store_row(row0 + r, r);
    }
}

__device__ __forceinline__ void accum_h8(float4 v, float* a) {
    const __half2* h2 = (const __half2*)&v;
#pragma unroll
    for (int j = 0; j < 4; ++j) {
        const float2 pr = __half22float2(h2[j]);
        a[2 * j]     += pr.x;
        a[2 * j + 1] += pr.y;
    }
}

// Fused agg(relu,bias) + gemm_next. Phase A interleaves 4 nodes per wave:
// per loop trip, 4 independent gathers issue before any use; trip count =
// max(deg) over the 4, not sum. hp_in is 64-ch fp16 (8 groups x 8 lanes).
template<int COUT>
__global__ __launch_bounds__(256) void fused_agg_gemm_kernel(
    const int* __restrict__ off, const int* __restrict__ csr,
    const float* __restrict__ dis, const __half* __restrict__ hp_in,
    const float* __restrict__ bias, const float* __restrict__ Wn,
    __half* __restrict__ hp_out, int N)
{
    constexpr int TX  = COUT / 4;
    constexpr int NPB = 256 / TX;    // rows per block: 16 or 32
    constexpr int NPW = NPB / 4;     // nodes per wave: 4 or 8
    __shared__ float Wl[64 * COUT];
    __shared__ float Al[NPB * 65];

    const int t = threadIdx.x;
    for (int i = t; i < 64 * COUT / 4; i += 256)
        ((float4*)Wl)[i] = ((const float4*)Wn)[i];

    const int wv = t >> 6, lane = t & 63;
    const int grp = lane >> 3, gl = lane & 7;

    float b[8];
#pragma unroll
    for (int j = 0; j < 8; ++j) b[j] = bias[gl * 8 + j];

    const int node0 = blockIdx.x * NPB + wv * NPW;

    for (int pass = 0; pass < NPW; pass += 4) {
        float acc[4][8];
#pragma unroll
        for (int j = 0; j < 4; ++j)
#pragma unroll
            for (int k = 0; k < 8; ++k) acc[j][k] = 0.0f;

        int e_[4], e1_[4];
#pragma unroll
        for (int j = 0; j < 4; ++j) {
            const int node = node0 + pass + j;
            if (node < N) {
                e_[j]  = off[node] + grp;
                e1_[j] = off[node + 1];
                if (grp == 0) {
                    const float4 v = *(const float4*)&hp_in[(size_t)node * 64 + gl * 8];
                    accum_h8(v, acc[j]);
                }
            } else { e_[j] = 0; e1_[j] = 0; }
        }

        int more = 1;
        while (more) {
            more = 0;
            float4 v[4];
            bool ok[4];
#pragma unroll
            for (int j = 0; j < 4; ++j) {
                ok[j] = (e_[j] < e1_[j]);
                if (ok[j]) {
                    const int sidx = csr[e_[j]];
                    v[j] = *(const float4*)&hp_in[(size_t)sidx * 64 + gl * 8];
                    e_[j] += 8;
                    more = 1;
                }
            }
#pragma unroll
            for (int j = 0; j < 4; ++j)
                if (ok[j]) accum_h8(v[j], acc[j]);
        }

#pragma unroll
        for (int j = 0; j < 4; ++j) {
#pragma unroll
            for (int d = 8; d < 64; d <<= 1)
#pragma unroll
                for (int k = 0; k < 8; ++k) acc[j][k] += __shfl_xor(acc[j][k], d);
            if (grp == 0) {
                const int node = node0 + pass + j;
                if (node < N) {
                    const float dn = dis[node];
                    const int row = wv * NPW + pass + j;
#pragma unroll
                    for (int k = 0; k < 8; ++k)
                        Al[row * 65 + gl * 8 + k] = fmaxf(fmaf(dn, acc[j][k], b[k]), 0.0f);
                }
            }
        }
    }
    __syncthreads();

    // Phase B: block GEMM Al[NPB x 64] @ Wn[64 x COUT] -> fp16 hp_out (*dis)
    const int tx = t % TX, ty = t / TX;
    const int gnode = blockIdx.x * NPB + ty;
    const int cb = tx * 4;
    float c0 = 0.f, c1 = 0.f, c2 = 0.f, c3 = 0.f;
#pragma unroll 8
    for (int k = 0; k < 64; ++k) {
        const float a = Al[ty * 65 + k];
        const float4 w4 = *(const float4*)&Wl[k * COUT + cb];
        c0 = fmaf(a, w4.x, c0);
        c1 = fmaf(a, w4.y, c1);
        c2 = fmaf(a, w4.z, c2);
        c3 = fmaf(a, w4.w, c3);
    }
    if (gnode < N) {
        const float d = dis[gnode];
        __half2 h0 = __float22half2_rn(make_float2(c0 * d, c1 * d));
        __half2 h1 = __float22half2_rn(make_float2(c2 * d, c3 * d));
        uint2 u;
        u.x = *(unsigned*)&h0;
        u.y = *(unsigned*)&h1;
        *(uint2*)&hp_out[(size_t)gnode * COUT + cb] = u;
    }
}

// Final aggregation (layer 3): 32-ch fp16 table, 4 nodes per wave interleaved
// (16 groups of 4 lanes), +bias, no relu, fp32 out. grid=(N+15)/16.
__global__ __launch_bounds__(256) void agg3_kernel(
    const int* __restrict__ off, const int* __restrict__ csr,
    const float* __restrict__ dis, const __half* __restrict__ hp,
    const float* __restrict__ bias, float* __restrict__ out, int N)
{
    const int t = threadIdx.x;
    const int wv = t >> 6, lane = t & 63;
    const int grp = lane >> 2, gl = lane & 3;   // 16 groups of 4 lanes
    const int node0 = blockIdx.x * 16 + wv * 4;

    float acc[4][8];
#pragma unroll
    for (int j = 0; j < 4; ++j)
#pragma unroll
        for (int k = 0; k < 8; ++k) acc[j][k] = 0.0f;

    int e_[4], e1_[4];
#pragma unroll
    for (int j = 0; j < 4; ++j) {
        const int node = node0 + j;
        if (node < N) {
            e_[j]  = off[node] + grp;
            e1_[j] = off[node + 1];
            if (grp == 0) {
                const float4 v = *(const float4*)&hp[(size_t)node * 32 + gl * 8];
                accum_h8(v, acc[j]);
            }
        } else { e_[j] = 0; e1_[j] = 0; }
    }

    int more = 1;
    while (more) {
        more = 0;
        float4 v[4];
        bool ok[4];
#pragma unroll
        for (int j = 0; j < 4; ++j) {
            ok[j] = (e_[j] < e1_[j]);
            if (ok[j]) {
                const int sidx = csr[e_[j]];
                v[j] = *(const float4*)&hp[(size_t)sidx * 32 + gl * 8];
                e_[j] += 16;
                more = 1;
            }
        }
#pragma unroll
        for (int j = 0; j < 4; ++j)
            if (ok[j]) accum_h8(v[j], acc[j]);
    }

#pragma unroll
    for (int j = 0; j < 4; ++j) {
#pragma unroll
        for (int d = 4; d < 64; d <<= 1)
#pragma unroll
            for (int k = 0; k < 8; ++k) acc[j][k] += __shfl_xor(acc[j][k], d);
        if (grp == 0) {
            const int node = node0 + j;
            if (node < N) {
                const float dn = dis[node];
                float v8[8];
#pragma unroll
                for (int k = 0; k < 8; ++k)
                    v8[k] = fmaf(dn, acc[j][k], bias[gl * 8 + k]);
                *(float4*)&out[(size_t)node * 32 + gl * 8]     = make_float4(v8[0], v8[1], v8[2], v8[3]);
                *(float4*)&out[(size_t)node * 32 + gl * 8 + 4] = make_float4(v8[4], v8[5], v8[6], v8[7]);
            }
        }
    }
}

static inline size_t align_up(size_t x) { return (x + 255) & ~(size_t)255; }

extern "C" void kernel_launch(void* const* d_in, const int* in_sizes, int n_in,
                              void* d_out, int out_size, void* d_ws, size_t ws_size,
                              hipStream_t stream) {
    const float* x   = (const float*)d_in[0];
    const int*  eidx = (const int*)d_in[1];
    const float* W1  = (const float*)d_in[2];
    const float* b1  = (const float*)d_in[3];
    const float* W2  = (const float*)d_in[4];
    const float* b2  = (const float*)d_in[5];
    const float* W3  = (const float*)d_in[6];
    const float* b3  = (const float*)d_in[7];
    float* out = (float*)d_out;

    const int N = in_sizes[0] / 128;   // 50000 (< 65536 required for packing)
    const int E = in_sizes[1] / 2;     // 800000
    const int* srcp = eidx;
    const int* dstp = eidx + E;
    const int nbuckets = (N + 255) >> 8;   // 196

    char* ws = (char*)d_ws;
    size_t o = 0;
    float* dis   = (float*)(ws + o);  o = align_up(o + (size_t)N * 4);
    int* off     = (int*)(ws + o);    o = align_up(o + (size_t)(N + 1) * 4);
    int* btot    = (int*)(ws + o);    o = align_up(o + 256 * 4);
    int* hist    = (int*)(ws + o);    o = align_up(o + 256 * 256 * 4);
    int* hoff    = (int*)(ws + o);    o = align_up(o + 256 * 256 * 4);
    int* bedge   = (int*)(ws + o);    o = align_up(o + (size_t)E * 4);
    int* csr     = (int*)(ws + o);    o = align_up(o + (size_t)E * 4);
    __half* H1   = (__half*)(ws + o); o = align_up(o + (size_t)N * 64 * 2);  // reused for H3
    __half* H2   = (__half*)(ws + o); o = align_up(o + (size_t)N * 64 * 2);
    __half* H3   = H1;   // H1 dead after fused2 completes (separate dispatch)

    const dim3 blk(256);

    // --- CSR build ---
    part_hist_kernel<<<dim3(256), blk, 0, stream>>>(dstp, hist, E, nbuckets);
    part_scan_kernel<<<dim3(nbuckets), blk, 0, stream>>>(hist, hoff, btot);
    part_scatter_kernel<<<dim3(256), blk, 0, stream>>>(srcp, dstp, hist, hoff, btot, bedge, E, nbuckets);
    bucket_csr_kernel<<<dim3(nbuckets), blk, 0, stream>>>(bedge, btot, csr, off, dis, N, nbuckets);

    // --- layer 1 GEMM: x[128] @ W1 -> H1 (fp16, *dis) ---
    gemm_scale_kernel<128, 64, 2><<<dim3((N + 31) / 32), blk, 0, stream>>>(x, W1, dis, H1, N);

    // --- fused agg1(relu,b1) + gemm2 -> H2 (fp16, *dis) ---
    fused_agg_gemm_kernel<64><<<dim3((N + 15) / 16), blk, 0, stream>>>(
        off, csr, dis, H1, b1, W2, H2, N);
    // --- fused agg2(relu,b2) + gemm3 -> H3 (fp16 32-ch, *dis) ---
    fused_agg_gemm_kernel<32><<<dim3((N + 31) / 32), blk, 0, stream>>>(
        off, csr, dis, H2, b2, W3, H3, N);
    // --- final agg3 (+b3, no relu) -> out (fp32) ---
    agg3_kernel<<<dim3((N + 15) / 16), blk, 0, stream>>>(off, csr, dis, H3, b3, out, N);
}

// Round 14
// 213.151 us; speedup vs baseline: 1.1631x; 1.1631x over previous
//
#include <hip/hip_runtime.h>
#include <hip/hip_fp16.h>

// ---------------------------------------------------------------------------
// BasketballGNN round 14: R11 fused/agg kernels restored (R13's interleaved
// gather defeated compiler pipelining — VALUBusy 2x, +15us/kernel). Kept from
// R13: P3 single-pass (counts from hist, no re-histogram) and P4 LDS ebuf
// staging. 8 dispatches: P1,P2a,P3,P4, gemm1, fused1, fused2, agg3.
// ---------------------------------------------------------------------------

#define P3CAP 3200   // >= chunk (3128 for E=800k)
#define P4CAP 8192   // >= max edges per 256-node bucket (avg 4082 for E=800k)

typedef float vf4 __attribute__((ext_vector_type(4)));

__device__ __forceinline__ int block_scan_incl(int v, int* s, int t) {
    s[t] = v;
    __syncthreads();
#pragma unroll
    for (int d = 1; d < 256; d <<= 1) {
        int a = (t >= d) ? s[t - d] : 0;
        __syncthreads();
        s[t] += a;
        __syncthreads();
    }
    return s[t];
}

__host__ __device__ __forceinline__ int chunk_of(int E) {
    return (((E + 255) / 256) + 3) & ~3;
}

// P1: per-chunk bucket histogram (counts kept for P3). grid=256.
__global__ __launch_bounds__(256) void part_hist_kernel(
    const int* __restrict__ dst, int* __restrict__ hist, int E, int nbuckets)
{
    __shared__ int lh[256];
    const int t = threadIdx.x;
    lh[t] = 0;
    __syncthreads();
    const int chunk = chunk_of(E);
    const int e0 = blockIdx.x * chunk;
    const int e1 = min(E, e0 + chunk);
    int e = e0 + t * 4;
    for (; e + 3 < e1; e += 1024) {
        const int4 d4 = *(const int4*)&dst[e];
        atomicAdd(&lh[d4.x >> 8], 1);
        atomicAdd(&lh[d4.y >> 8], 1);
        atomicAdd(&lh[d4.z >> 8], 1);
        atomicAdd(&lh[d4.w >> 8], 1);
    }
    for (; e < e1; ++e) atomicAdd(&lh[dst[e] >> 8], 1);
    __syncthreads();
    if (t < nbuckets) hist[t * 256 + blockIdx.x] = lh[t];
}

// P2a: per-bucket scan; offsets -> hoff (hist counts preserved), totals -> btot.
__global__ __launch_bounds__(256) void part_scan_kernel(
    const int* __restrict__ hist, int* __restrict__ hoff, int* __restrict__ btot)
{
    __shared__ int s[256];
    const int t = threadIdx.x;
    const int v = hist[blockIdx.x * 256 + t];
    const int inc = block_scan_incl(v, s, t);
    hoff[blockIdx.x * 256 + t] = inc - v;
    if (t == 255) btot[blockIdx.x] = inc;
}

// P3: single-pass LDS counting-sort of each chunk (counts read from hist).
__global__ __launch_bounds__(256) void part_scatter_kernel(
    const int* __restrict__ src, const int* __restrict__ dst,
    const int* __restrict__ hist, const int* __restrict__ hoff,
    const int* __restrict__ btot, int* __restrict__ bedge, int E, int nbuckets)
{
    __shared__ int gb[256], cur[256], s[256];
    __shared__ int stage[P3CAP];
    const int t = threadIdx.x;

    const int bv = (t < nbuckets) ? btot[t] : 0;
    const int binc = block_scan_incl(bv, s, t);
    const int bbase_t = binc - bv;
    __syncthreads();

    const int cnt_t = (t < nbuckets) ? hist[t * 256 + blockIdx.x] : 0;
    const int inc = block_scan_incl(cnt_t, s, t);
    const int excl = inc - cnt_t;
    cur[t] = excl;
    if (t < nbuckets) gb[t] = bbase_t + hoff[t * 256 + blockIdx.x] - excl;
    __syncthreads();

    const int chunk = chunk_of(E);
    const int e0 = blockIdx.x * chunk;
    const int e1 = min(E, e0 + chunk);
    {
        int e = e0 + t * 4;
        for (; e + 3 < e1; e += 1024) {
            const int4 d4 = *(const int4*)&dst[e];
            const int4 s4 = *(const int4*)&src[e];
            int r, b;
            b = d4.x >> 8; r = atomicAdd(&cur[b], 1);
            stage[r] = (s4.x & 0xffff) | ((d4.x & 255) << 16) | (b << 24);
            b = d4.y >> 8; r = atomicAdd(&cur[b], 1);
            stage[r] = (s4.y & 0xffff) | ((d4.y & 255) << 16) | (b << 24);
            b = d4.z >> 8; r = atomicAdd(&cur[b], 1);
            stage[r] = (s4.z & 0xffff) | ((d4.z & 255) << 16) | (b << 24);
            b = d4.w >> 8; r = atomicAdd(&cur[b], 1);
            stage[r] = (s4.w & 0xffff) | ((d4.w & 255) << 16) | (b << 24);
        }
        for (; e < e1; ++e) {
            const int dv = dst[e];
            const int b = dv >> 8;
            const int r = atomicAdd(&cur[b], 1);
            stage[r] = (src[e] & 0xffff) | ((dv & 255) << 16) | (b << 24);
        }
    }
    __syncthreads();
    const int cnt = e1 - e0;
    for (int i = t; i < cnt; i += 256) {
        const int p = stage[i];
        const int bucket = (int)((unsigned)p >> 24);
        bedge[gb[bucket] + i] = p;
    }
}

// P4: one block per bucket; bedge slice staged in LDS; -> csr, off, dis.
__global__ __launch_bounds__(256) void bucket_csr_kernel(
    const int* __restrict__ bedge, const int* __restrict__ btot,
    int* __restrict__ csr, int* __restrict__ off, float* __restrict__ dis,
    int N, int nbuckets)
{
    __shared__ int deg[256], cur[256], s[256];
    __shared__ int e01[2];
    __shared__ int ebuf[P4CAP];
    __shared__ int lcsr[P4CAP];
    const int t = threadIdx.x;
    const int b = blockIdx.x;

    const int bv = (t < nbuckets) ? btot[t] : 0;
    const int binc = block_scan_incl(bv, s, t);
    if (t == b) { e01[0] = binc - bv; e01[1] = binc; }
    deg[t] = 0;
    __syncthreads();
    const int e0 = e01[0], e1 = e01[1];
    const int m = e1 - e0;

    for (int i = t; i < m; i += 256) ebuf[i] = bedge[e0 + i];
    __syncthreads();
    for (int i = t; i < m; i += 256)
        atomicAdd(&deg[(ebuf[i] >> 16) & 255], 1);
    __syncthreads();
    const int v = deg[t];
    const int inc = block_scan_incl(v, s, t);
    cur[t] = inc - v;
    const int node = (b << 8) + t;
    if (node < N) {
        off[node + 1] = e0 + inc;
        dis[node] = rsqrtf((float)v + 1.0f);
        if (node == 0) off[0] = 0;
    }
    __syncthreads();
    for (int i = t; i < m; i += 256) {
        const int p = ebuf[i];
        const int pos = atomicAdd(&cur[(p >> 16) & 255], 1);
        lcsr[pos] = p & 0xffff;
    }
    __syncthreads();
    for (int i = t; i < m; i += 256)
        csr[e0 + i] = lcsr[i];
}

// GEMM (layer 1): hp[i,:] = fp16((in[i,:] @ W) * dis[i]).  TR=2 tile.
template<int K, int C, int TR>
__global__ __launch_bounds__(256) void gemm_scale_kernel(
    const float* __restrict__ in, const float* __restrict__ W,
    const float* __restrict__ dis, __half* __restrict__ hp, int N)
{
    constexpr int TX = C / 4;
    constexpr int R  = (256 / TX) * TR;
    __shared__ float Wl[K * C];

    const int t = threadIdx.x;
    for (int i = t; i < K * C / 4; i += 256)
        ((float4*)Wl)[i] = ((const float4*)W)[i];
    __syncthreads();

    const int tx = t % TX, ty = t / TX;
    const int cb = tx * 4;
    const int row0 = blockIdx.x * R + ty * TR;

    float acc[TR][4];
#pragma unroll
    for (int r = 0; r < TR; ++r) acc[r][0] = acc[r][1] = acc[r][2] = acc[r][3] = 0.0f;

    auto store_row = [&](int row, int r) {
        const float d = dis[row];
        __half2 h0 = __float22half2_rn(make_float2(acc[r][0] * d, acc[r][1] * d));
        __half2 h1 = __float22half2_rn(make_float2(acc[r][2] * d, acc[r][3] * d));
        uint2 u;
        u.x = *(unsigned*)&h0;
        u.y = *(unsigned*)&h1;
        *(uint2*)&hp[(size_t)row * C + cb] = u;
    };

    if (row0 + TR <= N) {
        const float* inp = in + (size_t)row0 * K;
#pragma unroll 4
        for (int k4 = 0; k4 < K / 4; ++k4) {
            float4 w0 = *(const float4*)&Wl[(k4 * 4 + 0) * C + cb];
            float4 w1 = *(const float4*)&Wl[(k4 * 4 + 1) * C + cb];
            float4 w2 = *(const float4*)&Wl[(k4 * 4 + 2) * C + cb];
            float4 w3 = *(const float4*)&Wl[(k4 * 4 + 3) * C + cb];
#pragma unroll
            for (int r = 0; r < TR; ++r) {
                const vf4 a = __builtin_nontemporal_load((const vf4*)&inp[r * K + k4 * 4]);
                acc[r][0] = fmaf(a.x, w0.x, acc[r][0]);
                acc[r][1] = fmaf(a.x, w0.y, acc[r][1]);
                acc[r][2] = fmaf(a.x, w0.z, acc[r][2]);
                acc[r][3] = fmaf(a.x, w0.w, acc[r][3]);
                acc[r][0] = fmaf(a.y, w1.x, acc[r][0]);
                acc[r][1] = fmaf(a.y, w1.y, acc[r][1]);
                acc[r][2] = fmaf(a.y, w1.z, acc[r][2]);
                acc[r][3] = fmaf(a.y, w1.w, acc[r][3]);
                acc[r][0] = fmaf(a.z, w2.x, acc[r][0]);
                acc[r][1] = fmaf(a.z, w2.y, acc[r][1]);
                acc[r][2] = fmaf(a.z, w2.z, acc[r][2]);
                acc[r][3] = fmaf(a.z, w2.w, acc[r][3]);
                acc[r][0] = fmaf(a.w, w3.x, acc[r][0]);
                acc[r][1] = fmaf(a.w, w3.y, acc[r][1]);
                acc[r][2] = fmaf(a.w, w3.z, acc[r][2]);
                acc[r][3] = fmaf(a.w, w3.w, acc[r][3]);
            }
        }
#pragma unroll
        for (int r = 0; r < TR; ++r) store_row(row0 + r, r);
    } else {
        for (int k = 0; k < K; ++k) {
            const float4 w4 = *(const float4*)&Wl[k * C + cb];
#pragma unroll
            for (int r = 0; r < TR; ++r) {
                const int row = row0 + r;
                const float a = (row < N) ? in[(size_t)row * K + k] : 0.0f;
                acc[r][0] = fmaf(a, w4.x, acc[r][0]);
                acc[r][1] = fmaf(a, w4.y, acc[r][1]);
                acc[r][2] = fmaf(a, w4.z, acc[r][2]);
                acc[r][3] = fmaf(a, w4.w, acc[r][3]);
            }
        }
#pragma unroll
        for (int r = 0; r < TR; ++r)
            if (row0 + r < N) store_row(row0 + r, r);
    }
}

// Fused agg(relu,bias) + gemm_next — R11 sequential form.
template<int COUT>
__global__ __launch_bounds__(256) void fused_agg_gemm_kernel(
    const int* __restrict__ off, const int* __restrict__ csr,
    const float* __restrict__ dis, const __half* __restrict__ hp_in,
    const float* __restrict__ bias, const float* __restrict__ Wn,
    __half* __restrict__ hp_out, int N)
{
    constexpr int TX  = COUT / 4;
    constexpr int NPB = 256 / TX;
    constexpr int NPW = NPB / 4;
    __shared__ float Wl[64 * COUT];
    __shared__ float Al[NPB * 65];

    const int t = threadIdx.x;
    for (int i = t; i < 64 * COUT / 4; i += 256)
        ((float4*)Wl)[i] = ((const float4*)Wn)[i];

    const int wv   = t >> 6;
    const int lane = t & 63;
    const int grp  = lane >> 3;
    const int gl   = lane & 7;

    float b[8];
#pragma unroll
    for (int j = 0; j < 8; ++j) b[j] = bias[gl * 8 + j];

    auto accum = [](float4 v, float* a) {
        const __half2* h2 = (const __half2*)&v;
#pragma unroll
        for (int j = 0; j < 4; ++j) {
            const float2 pr = __half22float2(h2[j]);
            a[2 * j]     += pr.x;
            a[2 * j + 1] += pr.y;
        }
    };

    const int node0 = blockIdx.x * NPB + wv * NPW;
    for (int nl = 0; nl < NPW; ++nl) {
        const int node = node0 + nl;
        if (node >= N) break;
        const int s0 = off[node];
        const int s1 = off[node + 1];

        float acc[8]  = {0, 0, 0, 0, 0, 0, 0, 0};
        float acc2[8] = {0, 0, 0, 0, 0, 0, 0, 0};

        if (grp == 0) {
            const float4 v = *(const float4*)&hp_in[(size_t)node * 64 + gl * 8];
            accum(v, acc);
        }
        int e = s0 + grp;
        for (; e + 8 < s1; e += 16) {
            const int sa = csr[e];
            const int sb = csr[e + 8];
            const float4 va = *(const float4*)&hp_in[(size_t)sa * 64 + gl * 8];
            const float4 vb = *(const float4*)&hp_in[(size_t)sb * 64 + gl * 8];
            accum(va, acc);
            accum(vb, acc2);
        }
        if (e < s1) {
            const int sa = csr[e];
            const float4 va = *(const float4*)&hp_in[(size_t)sa * 64 + gl * 8];
            accum(va, acc);
        }
#pragma unroll
        for (int j = 0; j < 8; ++j) acc[j] += acc2[j];
#pragma unroll
        for (int d = 8; d < 64; d <<= 1) {
#pragma unroll
            for (int j = 0; j < 8; ++j) acc[j] += __shfl_xor(acc[j], d);
        }
        if (grp == 0) {
            const float dn = dis[node];
            const int row = wv * NPW + nl;
#pragma unroll
            for (int j = 0; j < 8; ++j)
                Al[row * 65 + gl * 8 + j] = fmaxf(fmaf(dn, acc[j], b[j]), 0.0f);
        }
    }
    __syncthreads();

    const int tx = t % TX, ty = t / TX;
    const int gnode = blockIdx.x * NPB + ty;
    const int cb = tx * 4;
    float c0 = 0.f, c1 = 0.f, c2 = 0.f, c3 = 0.f;
#pragma unroll 8
    for (int k = 0; k < 64; ++k) {
        const float a = Al[ty * 65 + k];
        const float4 w4 = *(const float4*)&Wl[k * COUT + cb];
        c0 = fmaf(a, w4.x, c0);
        c1 = fmaf(a, w4.y, c1);
        c2 = fmaf(a, w4.z, c2);
        c3 = fmaf(a, w4.w, c3);
    }
    if (gnode < N) {
        const float d = dis[gnode];
        __half2 h0 = __float22half2_rn(make_float2(c0 * d, c1 * d));
        __half2 h1 = __float22half2_rn(make_float2(c2 * d, c3 * d));
        uint2 u;
        u.x = *(unsigned*)&h0;
        u.y = *(unsigned*)&h1;
        *(uint2*)&hp_out[(size_t)gnode * COUT + cb] = u;
    }
}

// Final aggregation (layer 3) — R11 form: 4 nodes/block, 16 groups of 4 lanes.
template<int C, bool RELU>
__global__ __launch_bounds__(256) void agg_kernel(
    const int* __restrict__ off, const int* __restrict__ csr,
    const float* __restrict__ dis, const __half* __restrict__ hp,
    const float* __restrict__ bias, float* __restrict__ out, int N)
{
    constexpr int GL = C / 8;
    constexpr int G  = 64 / GL;
    const int wv   = threadIdx.x >> 6;
    const int lane = threadIdx.x & 63;
    const int grp  = lane / GL;
    const int gl   = lane % GL;
    const int node = blockIdx.x * 4 + wv;
    if (node >= N) return;

    const int s0 = off[node];
    const int s1 = off[node + 1];

    float acc[8]  = {0, 0, 0, 0, 0, 0, 0, 0};
    float acc2[8] = {0, 0, 0, 0, 0, 0, 0, 0};

    auto accum = [](float4 v, float* a) {
        const __half2* h2 = (const __half2*)&v;
#pragma unroll
        for (int j = 0; j < 4; ++j) {
            const float2 pr = __half22float2(h2[j]);
            a[2 * j]     += pr.x;
            a[2 * j + 1] += pr.y;
        }
    };

    if (grp == 0) {
        const float4 v = *(const float4*)&hp[(size_t)node * C + gl * 8];
        accum(v, acc);
    }
    int e = s0 + grp;
    for (; e + G < s1; e += 2 * G) {
        const int sa = csr[e];
        const int sb = csr[e + G];
        const float4 va = *(const float4*)&hp[(size_t)sa * C + gl * 8];
        const float4 vb = *(const float4*)&hp[(size_t)sb * C + gl * 8];
        accum(va, acc);
        accum(vb, acc2);
    }
    if (e < s1) {
        const int sa = csr[e];
        const float4 va = *(const float4*)&hp[(size_t)sa * C + gl * 8];
        accum(va, acc);
    }
#pragma unroll
    for (int j = 0; j < 8; ++j) acc[j] += acc2[j];

#pragma unroll
    for (int d = GL; d < 64; d <<= 1) {
#pragma unroll
        for (int j = 0; j < 8; ++j) acc[j] += __shfl_xor(acc[j], d);
    }

    if (grp == 0) {
        const float dn = dis[node];
        float v[8];
#pragma unroll
        for (int j = 0; j < 8; ++j) {
            v[j] = fmaf(dn, acc[j], bias[gl * 8 + j]);
            if (RELU) v[j] = fmaxf(v[j], 0.f);
        }
        *(float4*)&out[(size_t)node * C + gl * 8]     = make_float4(v[0], v[1], v[2], v[3]);
        *(float4*)&out[(size_t)node * C + gl * 8 + 4] = make_float4(v[4], v[5], v[6], v[7]);
    }
}

static inline size_t align_up(size_t x) { return (x + 255) & ~(size_t)255; }

extern "C" void kernel_launch(void* const* d_in, const int* in_sizes, int n_in,
                              void* d_out, int out_size, void* d_ws, size_t ws_size,
                              hipStream_t stream) {
    const float* x   = (const float*)d_in[0];
    const int*  eidx = (const int*)d_in[1];
    const float* W1  = (const float*)d_in[2];
    const float* b1  = (const float*)d_in[3];
    const float* W2  = (const float*)d_in[4];
    const float* b2  = (const float*)d_in[5];
    const float* W3  = (const float*)d_in[6];
    const float* b3  = (const float*)d_in[7];
    float* out = (float*)d_out;

    const int N = in_sizes[0] / 128;   // 50000 (< 65536 required for packing)
    const int E = in_sizes[1] / 2;     // 800000
    const int* srcp = eidx;
    const int* dstp = eidx + E;
    const int nbuckets = (N + 255) >> 8;   // 196

    char* ws = (char*)d_ws;
    size_t o = 0;
    float* dis   = (float*)(ws + o);  o = align_up(o + (size_t)N * 4);
    int* off     = (int*)(ws + o);    o = align_up(o + (size_t)(N + 1) * 4);
    int* btot    = (int*)(ws + o);    o = align_up(o + 256 * 4);
    int* hist    = (int*)(ws + o);    o = align_up(o + 256 * 256 * 4);
    int* hoff    = (int*)(ws + o);    o = align_up(o + 256 * 256 * 4);
    int* bedge   = (int*)(ws + o);    o = align_up(o + (size_t)E * 4);
    int* csr     = (int*)(ws + o);    o = align_up(o + (size_t)E * 4);
    __half* H1   = (__half*)(ws + o); o = align_up(o + (size_t)N * 64 * 2);  // reused for H3
    __half* H2   = (__half*)(ws + o); o = align_up(o + (size_t)N * 64 * 2);
    __half* H3   = H1;   // H1 dead after fused2 completes (separate dispatch)

    const dim3 blk(256);

    // --- CSR build ---
    part_hist_kernel<<<dim3(256), blk, 0, stream>>>(dstp, hist, E, nbuckets);
    part_scan_kernel<<<dim3(nbuckets), blk, 0, stream>>>(hist, hoff, btot);
    part_scatter_kernel<<<dim3(256), blk, 0, stream>>>(srcp, dstp, hist, hoff, btot, bedge, E, nbuckets);
    bucket_csr_kernel<<<dim3(nbuckets), blk, 0, stream>>>(bedge, btot, csr, off, dis, N, nbuckets);

    // --- layer 1 GEMM: x[128] @ W1 -> H1 (fp16, *dis) ---
    gemm_scale_kernel<128, 64, 2><<<dim3((N + 31) / 32), blk, 0, stream>>>(x, W1, dis, H1, N);

    // --- fused agg1(relu,b1) + gemm2 -> H2 (fp16, *dis) ---
    fused_agg_gemm_kernel<64><<<dim3((N + 15) / 16), blk, 0, stream>>>(
        off, csr, dis, H1, b1, W2, H2, N);
    // --- fused agg2(relu,b2) + gemm3 -> H3 (fp16 32-ch, *dis) ---
    fused_agg_gemm_kernel<32><<<dim3((N + 31) / 32), blk, 0, stream>>>(
        off, csr, dis, H2, b2, W3, H3, N);
    // --- final agg3 (+b3, no relu) -> out (fp32) ---
    agg_kernel<32, false><<<dim3((N + 3) / 4), blk, 0, stream>>>(off, csr, dis, H3, b3, out, N);
}